// Round 8
// baseline (23.426 us; speedup 1.0000x reference)
//
#include <hip/hip_runtime.h>
#include <math.h>

#define LOG2E 1.4426950408889634f

typedef short short8 __attribute__((ext_vector_type(8)));
typedef float f32x4  __attribute__((ext_vector_type(4)));

__device__ inline unsigned short f2bf(float f) {   // f32 -> bf16 bits, RNE
    unsigned int u = __float_as_uint(f);
    return (unsigned short)((u + 0x7FFFu + ((u >> 16) & 1u)) >> 16);
}

__device__ inline unsigned int cvtpk_bf16(float lo, float hi) {
    unsigned int r;
    asm("v_cvt_pk_bf16_f32 %0, %1, %2" : "=v"(r) : "v"(lo), "v"(hi));
    return r;   // low16 = bf16(lo), high16 = bf16(hi)
}

// ONE dispatch. 256 blocks x 1024 threads (16 waves). Block owns 16 test
// rows; waves partition train (512 pts = 32 tiles each).
// Norm-in-MFMA: A k-slots 23,31 hold 1.0; B there holds -(0.5*log2e)*pn_half
// (each lane's own half-norm -> no cross-lane shuffle in the loop).
// 4-deep software pipeline: named slots, load(t+4) issued at consume(t).
__global__ __launch_bounds__(1024) void kde_fused(
    const float* __restrict__ testX, const float* __restrict__ trainX,
    float* __restrict__ out, int nTest, int nTrain, float Z)
{
    const int tid  = threadIdx.x;
    const int lane = tid & 63;
    const int w    = tid >> 6;            // wave 0..15
    const int NW   = 16;
    const int g    = lane >> 4;
    const int l4   = lane & 15;
    const int h    = g & 1;               // which 8-dim half this lane holds
    const int rowBase = blockIdx.x * 16;

    __shared__ float red[16][16];

    // ---- A fragment: rows rowBase..rowBase+15, [x_hi | x_lo], slots 23/31 = 1.0
    const int m = min(rowBase + l4, nTest - 1);
    const float4* xp = (const float4*)(testX + (size_t)m * 16);
    float4 x0 = xp[0], x1 = xp[1], x2 = xp[2], x3 = xp[3];
    float xs[16] = {x0.x,x0.y,x0.z,x0.w, x1.x,x1.y,x1.z,x1.w,
                    x2.x,x2.y,x2.z,x2.w, x3.x,x3.y,x3.z,x3.w};
    #pragma unroll
    for (int i = 0; i < 16; ++i) xs[i] *= LOG2E;
    float xn = 0.0f;
    #pragma unroll
    for (int i = 0; i < 16; ++i) xn = fmaf(xs[i], xs[i], xn);
    xn *= 0.5f / LOG2E;                   // 0.5*log2e*||x||^2 of row rowBase+l4

    short8 afrag;
    #pragma unroll
    for (int i = 0; i < 8; ++i) {
        float fx = xs[h * 8 + i];
        unsigned short hb = f2bf(fx);
        float hf = __uint_as_float((unsigned int)hb << 16);
        unsigned short lb = f2bf(fx - hf);
        afrag[i] = (short)((g < 2) ? hb : lb);   // k<16: hi, k>=16: lo
    }
    if (g >= 2) afrag[7] = (short)0x3F80;        // bf16(1.0) at k=23 / k=31

    // nx[r] = -(0.5*log2e*||x||^2) for this lane's C rows (one-time shuffle).
    float nx[4];
    #pragma unroll
    for (int r = 0; r < 4; ++r)
        nx[r] = -__shfl(xn, (lane & 48) + g * 4 + r);

    // ---- this wave's train slice ----
    const int per   = ((nTrain + NW * 16 - 1) / (NW * 16)) * 16;
    const int tbase = w * per;
    const int nt    = per >> 4;
    const int nMax  = nTrain - 1;
    const float NSC = 0.5f * LOG2E;

    auto LD = [&](int t, float4& a, float4& b) {
        int nc = min(tbase + t * 16 + l4, nMax);
        const float4* yp = (const float4*)(trainX + (size_t)nc * 16 + h * 8);
        a = yp[0]; b = yp[1];
    };
    // prep: half-norm -> B slot 7 (for g>=2); pack to bf16.
    auto PREP = [&](int t, const float4& za, const float4& zb, short8& bs) {
        float pn = ((za.x*za.x + za.y*za.y) + (za.z*za.z + za.w*za.w))
                 + ((zb.x*zb.x + zb.y*zb.y) + (zb.z*zb.z + zb.w*zb.w));
        const bool vn = tbase + t * 16 + l4 <= nMax;
        float pnv = vn ? -pn * NSC : -1e30f;     // invalid col -> exp2 -> 0
        float in7 = (g >= 2) ? pnv : zb.w;
        union { unsigned int u[4]; short8 s; } bb;
        bb.u[0] = cvtpk_bf16(za.x, za.y);
        bb.u[1] = cvtpk_bf16(za.z, za.w);
        bb.u[2] = cvtpk_bf16(zb.x, zb.y);
        bb.u[3] = cvtpk_bf16(zb.z, in7);
        bs = bb.s;
    };
    auto MEXP = [&](const short8& bs, float* rs) {
        f32x4 c;
        c[0] = nx[0]; c[1] = nx[1]; c[2] = nx[2]; c[3] = nx[3];
        c = __builtin_amdgcn_mfma_f32_16x16x32_bf16(afrag, bs, c, 0, 0, 0);
        rs[0] += __builtin_amdgcn_exp2f(c[0]);
        rs[1] += __builtin_amdgcn_exp2f(c[1]);
        rs[2] += __builtin_amdgcn_exp2f(c[2]);
        rs[3] += __builtin_amdgcn_exp2f(c[3]);
    };

    float rsA[4] = {0,0,0,0}, rsB[4] = {0,0,0,0};
    float4 a0,b0,a1,b1,a2,b2,a3,b3;
    short8 s0,s1,s2,s3;
    const int nt4 = nt & ~3;
    LD(0,a0,b0); LD(1,a1,b1); LD(2,a2,b2); LD(3,a3,b3);
    for (int t = 0; t < nt4; t += 4) {
        PREP(t+0,a0,b0,s0); LD(t+4,a0,b0); MEXP(s0,rsA);
        PREP(t+1,a1,b1,s1); LD(t+5,a1,b1); MEXP(s1,rsB);
        PREP(t+2,a2,b2,s2); LD(t+6,a2,b2); MEXP(s2,rsA);
        PREP(t+3,a3,b3,s3); LD(t+7,a3,b3); MEXP(s3,rsB);
    }
    // tail (nt not multiple of 4; unused at bench sizes)
    for (int t = nt4; t < nt; ++t) {
        float4 ta, tb; LD(t, ta, tb);
        short8 ts; PREP(t, ta, tb, ts);
        MEXP(ts, rsA);
    }

    // Reduce across the 16 columns (low-4 lane bits).
    float rs0 = rsA[0] + rsB[0], rs1 = rsA[1] + rsB[1];
    float rs2 = rsA[2] + rsB[2], rs3 = rsA[3] + rsB[3];
    #pragma unroll
    for (int off = 1; off <= 8; off <<= 1) {
        rs0 += __shfl_xor(rs0, off);
        rs1 += __shfl_xor(rs1, off);
        rs2 += __shfl_xor(rs2, off);
        rs3 += __shfl_xor(rs3, off);
    }
    if (l4 == 0) {
        red[w][g * 4 + 0] = rs0;
        red[w][g * 4 + 1] = rs1;
        red[w][g * 4 + 2] = rs2;
        red[w][g * 4 + 3] = rs3;
    }
    __syncthreads();

    if (tid < 16) {
        float s = 0.0f;
        #pragma unroll
        for (int k = 0; k < 16; ++k) s += red[k][tid];
        const int row = rowBase + tid;
        if (row < nTest) out[row] = __logf(s) - Z;
    }
}

extern "C" void kernel_launch(void* const* d_in, const int* in_sizes, int n_in,
                              void* d_out, int out_size, void* d_ws, size_t ws_size,
                              hipStream_t stream) {
    const float* testX  = (const float*)d_in[0];
    const float* trainX = (const float*)d_in[1];
    float* out = (float*)d_out;

    const int D = 16;
    const int nTest  = in_sizes[0] / D;   // 4096
    const int nTrain = in_sizes[1] / D;   // 8192

    const float Z = 0.5f * (float)D * logf(2.0f * (float)M_PI) + logf((float)nTrain);

    const int grid = (nTest + 15) / 16;   // 256 blocks, 16 rows each
    kde_fused<<<grid, 1024, 0, stream>>>(testX, trainX, out, nTest, nTrain, Z);
}

// Round 9
// 18.546 us; speedup vs baseline: 1.2631x; 1.2631x over previous
//
#include <hip/hip_runtime.h>
#include <math.h>

#define LOG2E 1.4426950408889634f
#define NWAVES 16
#define CHPTS  128   // train points staged per chunk per wave

typedef short short8 __attribute__((ext_vector_type(8)));
typedef float f32x4  __attribute__((ext_vector_type(4)));

__device__ inline unsigned short f2bf(float f) {   // f32 -> bf16 bits, RNE
    unsigned int u = __float_as_uint(f);
    return (unsigned short)((u + 0x7FFFu + ((u >> 16) & 1u)) >> 16);
}

__device__ inline unsigned int cvtpk_bf16(float lo, float hi) {
    unsigned int r;
    asm("v_cvt_pk_bf16_f32 %0, %1, %2" : "=v"(r) : "v"(lo), "v"(hi));
    return r;   // low16 = bf16(lo), high16 = bf16(hi)
}

// ONE dispatch. 256 blocks x 1024 threads (16 waves). Block owns 16 test
// rows; waves partition train (512 pts each). Each wave stages its slice
// into a PRIVATE 8KB LDS region in 128-pt chunks: packed 64B/point =
// 4 lane-group variants {dims0-7, dims8-15, dims0-6+norm0, dims8-14+norm1},
// slot-swizzled (v+p+(p>>2))&3 for 2-way (free) bank access. Inner loop:
// 1 ds_read_b128 + 1 MFMA + 4 exp2 per 16-pt tile. No barriers in loop
// (wave-private LDS, DS ops in-order per wave).
__global__ __launch_bounds__(1024) void kde_fused(
    const float* __restrict__ testX, const float* __restrict__ trainX,
    float* __restrict__ out, int nTest, int nTrain, float Z)
{
    const int tid  = threadIdx.x;
    const int lane = tid & 63;
    const int w    = tid >> 6;            // wave 0..15
    const int g    = lane >> 4;
    const int l4   = lane & 15;
    const int h    = g & 1;               // which 8-dim half this lane holds
    const int rowBase = blockIdx.x * 16;

    __shared__ short8 stage[NWAVES * CHPTS * 4];   // 128 KB
    __shared__ float  red[NWAVES][16];

    // ---- A fragment: rows rowBase..+15, [x_hi | x_lo], slots 23/31 = 1.0 ----
    const int m = min(rowBase + l4, nTest - 1);
    const float4* xp = (const float4*)(testX + (size_t)m * 16);
    float4 x0 = xp[0], x1 = xp[1], x2 = xp[2], x3 = xp[3];
    float xs[16] = {x0.x,x0.y,x0.z,x0.w, x1.x,x1.y,x1.z,x1.w,
                    x2.x,x2.y,x2.z,x2.w, x3.x,x3.y,x3.z,x3.w};
    #pragma unroll
    for (int i = 0; i < 16; ++i) xs[i] *= LOG2E;
    float xn = 0.0f;
    #pragma unroll
    for (int i = 0; i < 16; ++i) xn = fmaf(xs[i], xs[i], xn);
    xn *= 0.5f / LOG2E;                   // 0.5*log2e*||x||^2 of row rowBase+l4

    short8 afrag;
    #pragma unroll
    for (int i = 0; i < 8; ++i) {
        float fx = xs[h * 8 + i];
        unsigned short hb = f2bf(fx);
        float hf = __uint_as_float((unsigned int)hb << 16);
        unsigned short lb = f2bf(fx - hf);
        afrag[i] = (short)((g < 2) ? hb : lb);   // k<16: hi, k>=16: lo
    }
    if (g >= 2) afrag[7] = (short)0x3F80;        // bf16(1.0) at k=23 / k=31

    float nx[4];
    #pragma unroll
    for (int r = 0; r < 4; ++r)
        nx[r] = -__shfl(xn, (lane & 48) + g * 4 + r);

    // ---- wave's train slice / chunking ----
    const int perWave = ((nTrain + NWAVES * CHPTS - 1) / (NWAVES * CHPTS)) * CHPTS;
    const int nch  = perWave / CHPTS;
    const int tb   = w * perWave;
    const int nMax = nTrain - 1;

    // LDS addressing (units of short8 = 16B).
    const int vlane  = (g + l4 + (l4 >> 2)) & 3;           // read slot
    const int rdbase = (w * CHPTS + l4) * 4 + vlane;       // + t*64 per tile
    const int sw     = (lane + (lane >> 2));
    const int v0s = (0 + sw) & 3, v1s = (1 + sw) & 3;
    const int v2s = (2 + sw) & 3, v3s = (3 + sw) & 3;
    const int wr0 = (w * CHPTS + lane) * 4;                // p=lane; p=lane+64 -> +256

    struct PtRaw { float4 q0, q1, q2, q3; float inv; };
    auto LOADPT = [&](int c, int off) {
        PtRaw r;
        int gi = tb + c * CHPTS + off;
        int ci = min(gi, nMax);
        const float4* p = (const float4*)(trainX + (size_t)ci * 16);
        r.q0 = p[0]; r.q1 = p[1]; r.q2 = p[2]; r.q3 = p[3];
        r.inv = (gi <= nMax) ? 0.0f : 2e30f;
        return r;
    };
    auto WRITEPT = [&](const PtRaw& r, int sbase) {
        float pn0 = ((r.q0.x*r.q0.x + r.q0.y*r.q0.y) + (r.q0.z*r.q0.z + r.q0.w*r.q0.w))
                  + ((r.q1.x*r.q1.x + r.q1.y*r.q1.y) + (r.q1.z*r.q1.z + r.q1.w*r.q1.w))
                  + r.inv;
        float pn1 = ((r.q2.x*r.q2.x + r.q2.y*r.q2.y) + (r.q2.z*r.q2.z + r.q2.w*r.q2.w))
                  + ((r.q3.x*r.q3.x + r.q3.y*r.q3.y) + (r.q3.z*r.q3.z + r.q3.w*r.q3.w))
                  + r.inv;
        float n0 = -(0.5f * LOG2E) * pn0;
        float n1 = -(0.5f * LOG2E) * pn1;
        union { unsigned int u[4]; short8 s; } b0, b1, b2, b3;
        unsigned int u0 = cvtpk_bf16(r.q0.x, r.q0.y);
        unsigned int u1 = cvtpk_bf16(r.q0.z, r.q0.w);
        unsigned int u2 = cvtpk_bf16(r.q1.x, r.q1.y);
        unsigned int u3 = cvtpk_bf16(r.q1.z, r.q1.w);
        unsigned int u4 = cvtpk_bf16(r.q2.x, r.q2.y);
        unsigned int u5 = cvtpk_bf16(r.q2.z, r.q2.w);
        unsigned int u6 = cvtpk_bf16(r.q3.x, r.q3.y);
        unsigned int u7 = cvtpk_bf16(r.q3.z, r.q3.w);
        unsigned int u3n = cvtpk_bf16(r.q1.z, n0);
        unsigned int u7n = cvtpk_bf16(r.q3.z, n1);
        b0.u[0]=u0; b0.u[1]=u1; b0.u[2]=u2; b0.u[3]=u3;    // dims 0-7
        b1.u[0]=u4; b1.u[1]=u5; b1.u[2]=u6; b1.u[3]=u7;    // dims 8-15
        b2.u[0]=u0; b2.u[1]=u1; b2.u[2]=u2; b2.u[3]=u3n;   // dims 0-6 + n0
        b3.u[0]=u4; b3.u[1]=u5; b3.u[2]=u6; b3.u[3]=u7n;   // dims 8-14 + n1
        stage[sbase + v0s] = b0.s;
        stage[sbase + v1s] = b1.s;
        stage[sbase + v2s] = b2.s;
        stage[sbase + v3s] = b3.s;
    };

    float rsA[4] = {0,0,0,0}, rsB[4] = {0,0,0,0};
    auto INNER = [&]() {
        #pragma unroll
        for (int t = 0; t < CHPTS / 16; ++t) {
            short8 bf = stage[rdbase + t * 64];
            f32x4 cc;
            cc[0] = nx[0]; cc[1] = nx[1]; cc[2] = nx[2]; cc[3] = nx[3];
            cc = __builtin_amdgcn_mfma_f32_16x16x32_bf16(afrag, bf, cc, 0, 0, 0);
            if (t & 1) {
                rsB[0] += __builtin_amdgcn_exp2f(cc[0]);
                rsB[1] += __builtin_amdgcn_exp2f(cc[1]);
                rsB[2] += __builtin_amdgcn_exp2f(cc[2]);
                rsB[3] += __builtin_amdgcn_exp2f(cc[3]);
            } else {
                rsA[0] += __builtin_amdgcn_exp2f(cc[0]);
                rsA[1] += __builtin_amdgcn_exp2f(cc[1]);
                rsA[2] += __builtin_amdgcn_exp2f(cc[2]);
                rsA[3] += __builtin_amdgcn_exp2f(cc[3]);
            }
        }
    };

    // Prologue: stage chunk 0.
    {
        PtRaw a0 = LOADPT(0, lane);
        PtRaw a1 = LOADPT(0, lane + 64);
        WRITEPT(a0, wr0);
        WRITEPT(a1, wr0 + 256);
    }
    // Pipeline: load(c+1) || inner(c) || write(c+1).
    for (int c = 0; c < nch; ++c) {
        PtRaw b0, b1;
        const bool more = (c + 1 < nch);
        if (more) { b0 = LOADPT(c + 1, lane); b1 = LOADPT(c + 1, lane + 64); }
        INNER();
        if (more) { WRITEPT(b0, wr0); WRITEPT(b1, wr0 + 256); }
    }

    // Reduce across the 16 columns (low-4 lane bits).
    float rs0 = rsA[0] + rsB[0], rs1 = rsA[1] + rsB[1];
    float rs2 = rsA[2] + rsB[2], rs3 = rsA[3] + rsB[3];
    #pragma unroll
    for (int off = 1; off <= 8; off <<= 1) {
        rs0 += __shfl_xor(rs0, off);
        rs1 += __shfl_xor(rs1, off);
        rs2 += __shfl_xor(rs2, off);
        rs3 += __shfl_xor(rs3, off);
    }
    if (l4 == 0) {
        red[w][g * 4 + 0] = rs0;
        red[w][g * 4 + 1] = rs1;
        red[w][g * 4 + 2] = rs2;
        red[w][g * 4 + 3] = rs3;
    }
    __syncthreads();

    if (tid < 16) {
        float s = 0.0f;
        #pragma unroll
        for (int k = 0; k < NWAVES; ++k) s += red[k][tid];
        const int row = rowBase + tid;
        if (row < nTest) out[row] = __logf(s) - Z;
    }
}

extern "C" void kernel_launch(void* const* d_in, const int* in_sizes, int n_in,
                              void* d_out, int out_size, void* d_ws, size_t ws_size,
                              hipStream_t stream) {
    const float* testX  = (const float*)d_in[0];
    const float* trainX = (const float*)d_in[1];
    float* out = (float*)d_out;

    const int D = 16;
    const int nTest  = in_sizes[0] / D;   // 4096
    const int nTrain = in_sizes[1] / D;   // 8192

    const float Z = 0.5f * (float)D * logf(2.0f * (float)M_PI) + logf((float)nTrain);

    const int grid = (nTest + 15) / 16;   // 256 blocks, 16 rows each
    kde_fused<<<grid, 1024, 0, stream>>>(testX, trainX, out, nTest, nTrain, Z);
}